// Round 7
// baseline (221.629 us; speedup 1.0000x reference)
//
#include <hip/hip_runtime.h>
#include <math.h>

#define S_DIM 8
#define N_DIM 2048
#define K_DIM 64
#define APW 4          // atoms per wave
#define WAVES 4        // waves per block (independent, no cross-wave sync in loop)
// h1 tile buffer geometry: 4x16 bf16 tiles (128 B) + 16 B pad, [q_t][jt] grid
#define TQ 144         // tile stride, bytes
#define TJ (4 * TQ)    // jt stride
#define H1B (4 * TJ)   // h1 buffer: 16 tiles = 2304 B (single buffer)
#define SLICE 3392     // per-wave LDS slice: s_rt 1088 + h1t/s_A 2304

typedef __attribute__((ext_vector_type(8))) short bf16x8;
typedef __attribute__((ext_vector_type(4))) float f32x4;
typedef __attribute__((ext_vector_type(4))) int   i32x4;
typedef __attribute__((ext_vector_type(2))) int   i32x2;

__device__ __forceinline__ unsigned asu(float x) {
    union { float f; unsigned u; } v; v.f = x; return v.u;
}
__device__ __forceinline__ unsigned short f2bf(float x) {
    unsigned u = asu(x);
    return (unsigned short)((u + 0x7FFFu + ((u >> 16) & 1u)) >> 16);
}
__device__ __forceinline__ float lo16f(int d) {
    union { unsigned u; float f; } v; v.u = ((unsigned)d) << 16; return v.f;
}
__device__ __forceinline__ float hi16f(int d) {
    union { unsigned u; float f; } v; v.u = ((unsigned)d) & 0xFFFF0000u; return v.f;
}
// RNE packed pair — integer-ALU form, bit-identical to baseline.
__device__ __forceinline__ unsigned rne_pk(float x, float y) {
    unsigned ux = asu(x), uy = asu(y);
    return ((ux + 0x7FFFu + ((ux >> 16) & 1u)) >> 16) |
           ((uy + 0x7FFFu + ((uy >> 16) & 1u)) & 0xFFFF0000u);
}
// truncation packed pair (L2 g operand, as baseline)
__device__ __forceinline__ unsigned trn_pk(float x, float y) {
    return (asu(x) >> 16) | (asu(y) & 0xFFFF0000u);
}
// Wave-local LDS fence (slices are wave-private; weights are read-only after
// the one startup barrier). Proven correct R3/R4/R6.
__device__ __forceinline__ void lds_fence() {
    asm volatile("s_waitcnt lgkmcnt(0)" ::: "memory");
    __builtin_amdgcn_sched_barrier(0);
}
// K<=16 MFMA from two packed bf16-pair dwords per operand (zero-padded K=32).
__device__ __forceinline__ f32x4 mfma_k16(unsigned a0, unsigned a1,
                                          unsigned b0, unsigned b1, f32x4 c) {
    union { i32x4 i; bf16x8 b; } ua, ub;
    ua.i = (i32x4){(int)a0, (int)a1, 0, 0};
    ub.i = (i32x4){(int)b0, (int)b1, 0, 0};
    return __builtin_amdgcn_mfma_f32_16x16x32_bf16(ua.b, ub.b, c, 0, 0, 0);
}

// ---------------------------------------------------------------------------
// Prep: packed td table + bf16 weights (unchanged).
// ---------------------------------------------------------------------------
__global__ __launch_bounds__(256) void prep_kernel(
        const float* __restrict__ ew0, const float* __restrict__ eb0,
        const float* __restrict__ ew1, const float* __restrict__ eb1,
        const float* __restrict__ fw0, const float* __restrict__ fb0,
        const float* __restrict__ fw1, const float* __restrict__ fb1,
        const float* __restrict__ gw0, const float* __restrict__ gw1,
        unsigned* __restrict__ td_pk,
        unsigned short* __restrict__ w0t, unsigned short* __restrict__ w1t) {
    __shared__ float l_ew0[32], l_eb0[16], l_ew1[512], l_eb1[32];
    __shared__ float l_fw0[1024], l_fb0[32], l_fw1[992], l_fb1[31];
    __shared__ float l_h[4][2][16];
    __shared__ float l_tv[4][32];
    __shared__ float l_f1[4][32];
    __shared__ float l_td[4][32];

    const int tid = threadIdx.x;
    if (tid < 32) l_ew0[tid] = ew0[tid];
    if (tid < 16) l_eb0[tid] = eb0[tid];
    for (int i = tid; i < 512; i += 256) l_ew1[i] = ew1[i];
    if (tid < 32) l_eb1[tid] = eb1[tid];
    for (int i = tid; i < 1024; i += 256) l_fw0[i] = fw0[i];
    if (tid < 32) l_fb0[tid] = fb0[tid];
    for (int i = tid; i < 992; i += 256) l_fw1[i] = fw1[i];
    if (tid < 31) l_fb1[tid] = fb1[tid];
    __syncthreads();

    if (tid < 128) {
        const int p = tid >> 5, ord = (tid >> 4) & 1, j = tid & 15;
        const float c = (float)(p >> 1), t = (float)(p & 1);
        const float x0 = ord ? t : c;
        const float x1 = ord ? c : t;
        l_h[p][ord][j] = fmaxf(x0 * l_ew0[j] + x1 * l_ew0[16 + j] + l_eb0[j], 0.f);
    }
    __syncthreads();
    if (tid < 128) {
        const int p = tid >> 5, j = tid & 31;
        float acc = 0.f;
#pragma unroll
        for (int ord = 0; ord < 2; ord++) {
            float v = l_eb1[j];
#pragma unroll
            for (int i = 0; i < 16; i++) v += l_h[p][ord][i] * l_ew1[i * 32 + j];
            acc += fmaxf(v, 0.f);
        }
        l_tv[p][j] = acc;
    }
    __syncthreads();
    if (tid < 128) {
        const int p = tid >> 5, j = tid & 31;
        float v = l_fb0[j];
#pragma unroll
        for (int i = 0; i < 32; i++) v += l_tv[p][i] * l_fw0[i * 32 + j];
        l_f1[p][j] = fmaxf(v, 0.f);
    }
    __syncthreads();
    if (tid < 128) {
        const int p = tid >> 5, j = tid & 31;
        if (j < 31) {
            float v = l_fb1[j];
#pragma unroll
            for (int i = 0; i < 32; i++) v += l_f1[p][i] * l_fw1[i * 31 + j];
            l_td[p][j] = fmaxf(v, 0.f);
        } else {
            l_td[p][31] = 0.f;
        }
    }
    __syncthreads();
    if (tid < 64) {   // td_pk[p*16+i] = bf(td[2i]) | bf(td[2i+1])<<16
        const int p = tid >> 4, i = tid & 15;
        const unsigned lo = f2bf(l_td[p][2 * i]);
        const unsigned hi = (i == 15) ? 0u : (unsigned)f2bf(l_td[p][2 * i + 1]);
        td_pk[tid] = lo | (hi << 16);
    }

    for (int idx = tid; idx < 2048; idx += 256) {   // W0T[j*32+i] = gw0[i][j]
        const int j = idx >> 5, i = idx & 31;
        w0t[idx] = f2bf(gw0[i * 64 + j]);
    }
    for (int idx = tid; idx < 8192; idx += 256) {   // W1T[e*64+j] = gw1[j][e]
        const int e = idx >> 6, j = idx & 63;
        w1t[idx] = f2bf(gw1[j * 128 + e]);
    }
}

// ---------------------------------------------------------------------------
// Main. OCCUPANCY DIAGNOSIS (R0/R4/R6 all ~80us regardless of instruction
// count): combined VGPR+AGPR was ~180 (w1f alone = 64 regs) -> 2 waves/SIMD
// (m69 quantum: halves at 128/256) -> 6-8 waves/CU -> latency chains exposed.
// FIX: w1f + b0 demoted to block-shared LDS (rotation-swizzled w1, even bank
// use); s_st eliminated (st rebuilt from 256B td table + 1 ds_bpermute of
// packed {pair,msk,sij}); h1 single-buffered; s_A overlaid. 4 independent
// waves/block share the weight staging; one __syncthreads at start only.
// Target: combined regs <=128 -> 4 waves/SIMD; 12-16 waves/CU.
// launch_bounds(256,3): cap ~170 — guaranteed no spill (R3 lesson).
// ---------------------------------------------------------------------------
__global__ __launch_bounds__(256, 3) void descr_mfma(
    const float* __restrict__ inputs, const int* __restrict__ input_types,
    const int* __restrict__ neigh_list, const float* __restrict__ length,
    const float* __restrict__ gb0, const float* __restrict__ gb1,
    const unsigned* __restrict__ td_pk, const unsigned short* __restrict__ w0t,
    const unsigned short* __restrict__ w1t, float* __restrict__ out)
{
    __shared__ __align__(16) char s_pool[WAVES * SLICE];   // 13568 B
    __shared__ __align__(16) char s_w1[16384];             // swizzled W1T
    __shared__ unsigned s_tdpk[64];                        // td table
    __shared__ float s_gb0f[64];                           // bias b0

    const int tid = threadIdx.x;
    const int lane = tid & 63;
    const int w = tid >> 6;
    const int l15 = lane & 15;
    const int q = lane >> 4;

    // ---- block-cooperative staging (once) -------------------------------
    if (tid < 64) { s_tdpk[tid] = td_pk[tid]; s_gb0f[tid] = gb0[tid]; }
    for (int m = tid; m < 1024; m += 256) {   // 1024 x 16B chunks of W1T
        const int e = m >> 3, c = m & 7;
        const i32x4 v = *(const i32x4*)&w1t[e * 64 + c * 8];
        *(i32x4*)(s_w1 + e * 128 + (((c + e) & 7) << 4)) = v;  // rotate chunks
    }
    __syncthreads();   // ONLY block barrier; loop below is wave-independent

    // ---- per-wave slice pointers ----------------------------------------
    char* const slice = s_pool + w * SLICE;
    float* const s_rt = (float*)slice;              // 1088 B
    char*  const h1t  = slice + 1088;               // 2304 B tiles
    float* const s_A  = (float*)(slice + 1088);     // overlay (h1 dead in D)
    const unsigned h1u = (unsigned)(unsigned long long)(const void*)h1t;

    const int wroff = (l15 >> 2) * TQ + (l15 & 3) * 32 + q * 8;          // tile write
    const unsigned troff = h1u + (unsigned)(q * TQ + (l15 >> 2) * 32 + (l15 & 3) * 8);
    const int aoff  = (l15 >> 2) * TQ + (l15 & 3) * 32 + (q & 1) * 16;   // L2 read
    const char* const w1r = s_w1 + l15 * 128;
    const int wo0 = ((q + l15) & 7) << 4;            // chunk rot, j = q*8..
    const int wo1 = ((q + 4 + l15) & 7) << 4;        // chunk rot, j = 32+q*8..

    // static small fragments (registers)
    bf16x8 w0f[4];
#pragma unroll
    for (int nt = 0; nt < 4; nt++)
        w0f[nt] = *(const bf16x8*)&w0t[(nt * 16 + l15) * 32 + q * 8];
    float b1f[8];
#pragma unroll
    for (int et = 0; et < 8; et++) b1f[et] = gb1[et * 16 + l15];

    const float Lx = length[0], Ly = length[1], Lz = length[2];
    const float iLx = 1.f / Lx, iLy = 1.f / Ly, iLz = 1.f / Lz;
    const f32x4 zf = {0.f, 0.f, 0.f, 0.f};

    const int abase = (blockIdx.x * WAVES + w) * APW;
    const int sidx = abase >> 11;   // APW atoms of a wave share s (16 | 2048)

    // geometry pipeline state (current atom, prefetched one iter ahead)
    int   cnb  = neigh_list[abase * K_DIM + lane];
    float ccx  = inputs[abase * 3 + 0];
    float ccy  = inputs[abase * 3 + 1];
    float ccz  = inputs[abase * 3 + 2];
    int   cct  = input_types[abase];
    int   cidx0 = cnb < 0 ? 0 : cnb;
    float cpx  = inputs[(sidx * N_DIM + cidx0) * 3 + 0];
    float cpy  = inputs[(sidx * N_DIM + cidx0) * 3 + 1];
    float cpz  = inputs[(sidx * N_DIM + cidx0) * 3 + 2];
    int   cntp = input_types[sidx * N_DIM + cidx0];

    for (int aa = 0; aa < APW; aa++) {
        const int atom = abase + aa;
        const bool pf = (aa + 1 < APW);

        // stage-A prefetch for next atom
        int nnb = 0, nct = 0; float ncx = 0.f, ncy = 0.f, ncz = 0.f;
        if (pf) {
            nnb = neigh_list[(atom + 1) * K_DIM + lane];
            ncx = inputs[(atom + 1) * 3 + 0];
            ncy = inputs[(atom + 1) * 3 + 1];
            ncz = inputs[(atom + 1) * 3 + 2];
            nct = input_types[atom + 1];
        }

        lds_fence();   // s_rt overwrite vs prior rtp reads; s_A reads done

        // ---- geometry -> s_rt + packed per-lane info (NO st staging)
        unsigned pinfo;
        {
            const bool msk = cnb < 0;
            float dx = cpx - ccx;
            float dy = cpy - ccy;
            float dz = cpz - ccz;
            dx -= Lx * rintf(dx * iLx);
            dy -= Ly * rintf(dy * iLy);
            dz -= Lz * rintf(dz * iLz);
            const float rsq = dx * dx + dy * dy + dz * dz;
            const float r = sqrtf(rsq > 0.f ? rsq : 1.f);
            const float inv = 1.f / r;
            float sw;
            if (r < 6.f) sw = inv;
            else if (r < 12.f) {
                const float u = (r - 6.f) * (1.f / 6.f);
                sw = inv * (0.5f * __cosf(3.14159265358979323846f * u) + 0.5f);
            } else sw = 0.f;
            const bool valid = (!msk) && (rsq > 0.f);
            const float sij = valid ? sw : 0.f;
            const float f = sij * inv;
            s_rt[0 * 68 + lane] = sij;
            s_rt[1 * 68 + lane] = dx * f;
            s_rt[2 * 68 + lane] = dy * f;
            s_rt[3 * 68 + lane] = dz * f;
            pinfo = ((unsigned)f2bf(sij) << 16) |
                    (unsigned)((cct << 1) + cntp) | (msk ? 256u : 0u);
        }
        lds_fence();

        // ---- rt^T fragments, packed RNE pairs
        unsigned rtp[4][2];
#pragma unroll
        for (int a = 0; a < 4; a++) {
            const f32x4 rv = *(const f32x4*)&s_rt[(l15 & 3) * 68 + a * 16 + q * 4];
            rtp[a][0] = rne_pk(rv[0], rv[1]);
            rtp[a][1] = rne_pk(rv[2], rv[3]);
        }

        int nidx = 0, nntp = 0; float npx = 0.f, npy = 0.f, npz = 0.f;
        f32x4 Bj[4] = {zf, zf, zf, zf};
        f32x4 AT[8] = {zf, zf, zf, zf, zf, zf, zf, zf};

        // ---- per-16-k chunk: rebuild st from table -> L1^T -> tiles -> Bj/L2
#pragma unroll
        for (int mt = 0; mt < 4; mt++) {
            // neighbor-k info for k = mt*16+l15 (same source lane for all q)
            const unsigned pk =
                (unsigned)__builtin_amdgcn_ds_bpermute((mt * 16 + l15) << 2, (int)pinfo);
            const unsigned pair = pk & 3u;
            const unsigned zm = (pk & 256u) ? 0u : 0xFFFFFFFFu;
            const unsigned ksij = pk & 0xFFFF0000u;
            const unsigned* trow = &s_tdpk[pair * 16];
            // st[k][i=q*8..+7] (B-operand) and residual dword-pairs
            i32x4 tq = *(const i32x4*)&trow[q * 4];
            i32x2 rd0 = *(const i32x2*)&trow[2 * q];
            i32x2 rd1 = *(const i32x2*)&trow[8 + 2 * q];
            tq[0] = (int)((unsigned)tq[0] & zm);
            tq[1] = (int)((unsigned)tq[1] & zm);
            tq[2] = (int)((unsigned)tq[2] & zm);
            tq[3] = (int)((unsigned)tq[3] & zm);
            rd0[0] = (int)((unsigned)rd0[0] & zm);
            rd0[1] = (int)((unsigned)rd0[1] & zm);
            rd1[0] = (int)((unsigned)rd1[0] & zm);
            rd1[1] = (int)((unsigned)rd1[1] & zm);
            if (q == 3) {   // i=31 <- sij (tq dword3 hi16; rd1 dword1 hi16)
                tq[3]  = (int)(((unsigned)tq[3]  & 0xFFFFu) | ksij);
                rd1[1] = (int)(((unsigned)rd1[1] & 0xFFFFu) | ksij);
            }
            union { i32x4 i; bf16x8 b; } ua; ua.i = tq;
            const bf16x8 afr = ua.b;

            f32x4 c1[4];
#pragma unroll
            for (int jt = 0; jt < 4; jt++)   // TRANSPOSED L1: A=W0^T, B=st
                c1[jt] = __builtin_amdgcn_mfma_f32_16x16x32_bf16(w0f[jt], afr, zf, 0, 0, 0);

            // epilogue: lane holds h1[k=mt*16+l15][j=jt*16+q*4+reg]
#pragma unroll
            for (int jt = 0; jt < 4; jt++) {
                const f32x4 bb = *(const f32x4*)&s_gb0f[jt * 16 + q * 4];
                const i32x2 rr = (jt & 1) ? rd1 : rd0;
                const float h0 = fmaxf(c1[jt][0] + bb[0], 0.f) + lo16f(rr[0]);
                const float h1 = fmaxf(c1[jt][1] + bb[1], 0.f) + hi16f(rr[0]);
                const float h2 = fmaxf(c1[jt][2] + bb[2], 0.f) + lo16f(rr[1]);
                const float h3 = fmaxf(c1[jt][3] + bb[3], 0.f) + hi16f(rr[1]);
                i32x2 pkv;
                pkv[0] = (int)rne_pk(h0, h1);
                pkv[1] = (int)rne_pk(h2, h3);
                *(i32x2*)(h1t + wroff + jt * TJ) = pkv;
            }
            if (mt == 0 && pf) {   // stage-B prefetch (ample slack)
                nidx = nnb < 0 ? 0 : nnb;
                const int nbase = (sidx * N_DIM + nidx) * 3;
                npx = inputs[nbase + 0];
                npy = inputs[nbase + 1];
                npz = inputs[nbase + 2];
                nntp = input_types[sidx * N_DIM + nidx];
            }
            lds_fence();   // tile writes -> reads handoff (same-wave DS in order)

            // Bj B-operand: cooperative tr-read (R6-verified addressing)
            i32x2 t0, t1, t2, t3;
            asm volatile("ds_read_b64_tr_b16 %0, %1" : "=v"(t0) : "v"(troff));
            asm volatile("ds_read_b64_tr_b16 %0, %1" : "=v"(t1) : "v"(troff + TJ));
            asm volatile("ds_read_b64_tr_b16 %0, %1" : "=v"(t2) : "v"(troff + 2 * TJ));
            asm volatile("ds_read_b64_tr_b16 %0, %1" : "=v"(t3) : "v"(troff + 3 * TJ));
            asm volatile("s_waitcnt lgkmcnt(0)" ::: "memory");
            __builtin_amdgcn_sched_barrier(0);
            Bj[0] = mfma_k16(rtp[mt][0], rtp[mt][1], (unsigned)t0[0], (unsigned)t0[1], Bj[0]);
            Bj[1] = mfma_k16(rtp[mt][0], rtp[mt][1], (unsigned)t1[0], (unsigned)t1[1], Bj[1]);
            Bj[2] = mfma_k16(rtp[mt][0], rtp[mt][1], (unsigned)t2[0], (unsigned)t2[1], Bj[2]);
            Bj[3] = mfma_k16(rtp[mt][0], rtp[mt][1], (unsigned)t3[0], (unsigned)t3[1], Bj[3]);

            // L2: A-frag h1[k=mt*16+l15][j] from tiles; W1 from swizzled LDS
            const bf16x8 a0 = *(const bf16x8*)(h1t + aoff + (q >> 1) * TJ);
            const bf16x8 a1 = *(const bf16x8*)(h1t + aoff + (2 + (q >> 1)) * TJ);
#pragma unroll
            for (int et = 0; et < 8; et++) {
                const bf16x8 wf0 = *(const bf16x8*)(w1r + et * 2048 + wo0);
                const bf16x8 wf1 = *(const bf16x8*)(w1r + et * 2048 + wo1);
                f32x4 c2 = __builtin_amdgcn_mfma_f32_16x16x32_bf16(a0, wf0, zf, 0, 0, 0);
                c2 = __builtin_amdgcn_mfma_f32_16x16x32_bf16(a1, wf1, c2, 0, 0, 0);
                const float g0 = fmaxf(c2[0] + b1f[et], 0.f);
                const float g1 = fmaxf(c2[1] + b1f[et], 0.f);
                const float g2 = fmaxf(c2[2] + b1f[et], 0.f);
                const float g3 = fmaxf(c2[3] + b1f[et], 0.f);
                AT[et] = mfma_k16(rtp[mt][0], rtp[mt][1],
                                  trn_pk(g0, g1), trn_pk(g2, g3), AT[et]);
            }
        }

        // ---- A = AT + Bj[e&3]; rows d=0..3 live in q==0 lanes
        if (lane < 16) {
#pragma unroll
            for (int et = 0; et < 8; et++) {
                const f32x4 v = AT[et] + Bj[et & 3];
                *(f32x4*)&s_A[(et * 16 + lane) * 4] = v;
            }
        }
        lds_fence();

        // ---- D[e][m] = dot(A[e], A[m]); coalesced float4 stores
        {
            const int m0 = (lane & 3) * 4;
            const int er = lane >> 2;
            f32x4 Am[4];
#pragma unroll
            for (int t = 0; t < 4; t++) Am[t] = *(const f32x4*)&s_A[(m0 + t) * 4];
            float* op = out + (size_t)atom * 2048;
#pragma unroll
            for (int g = 0; g < 8; g++) {
                const int e = g * 16 + er;
                const f32x4 Ae = *(const f32x4*)&s_A[e * 4];
                f32x4 o;
                o[0] = Ae[0]*Am[0][0] + Ae[1]*Am[0][1] + Ae[2]*Am[0][2] + Ae[3]*Am[0][3];
                o[1] = Ae[0]*Am[1][0] + Ae[1]*Am[1][1] + Ae[2]*Am[1][2] + Ae[3]*Am[1][3];
                o[2] = Ae[0]*Am[2][0] + Ae[1]*Am[2][1] + Ae[2]*Am[2][2] + Ae[3]*Am[2][3];
                o[3] = Ae[0]*Am[3][0] + Ae[1]*Am[3][1] + Ae[2]*Am[3][2] + Ae[3]*Am[3][3];
                *(f32x4*)&op[e * 16 + m0] = o;
            }
        }

        // rotate prefetched geometry state
        cnb = nnb; ccx = ncx; ccy = ncy; ccz = ncz; cct = nct;
        cpx = npx; cpy = npy; cpz = npz; cntp = nntp;
    }
}

extern "C" void kernel_launch(void* const* d_in, const int* in_sizes, int n_in,
                              void* d_out, int out_size, void* d_ws, size_t ws_size,
                              hipStream_t stream) {
    (void)in_sizes; (void)n_in; (void)out_size; (void)ws_size;
    const float* inputs      = (const float*)d_in[0];
    const int*   input_types = (const int*)d_in[1];
    const int*   neigh_list  = (const int*)d_in[2];
    const float* length      = (const float*)d_in[3];
    const float* ew0 = (const float*)d_in[4];
    const float* eb0 = (const float*)d_in[5];
    const float* ew1 = (const float*)d_in[6];
    const float* eb1 = (const float*)d_in[7];
    const float* fw0 = (const float*)d_in[8];
    const float* fb0 = (const float*)d_in[9];
    const float* fw1 = (const float*)d_in[10];
    const float* fb1 = (const float*)d_in[11];
    const float* gw0 = (const float*)d_in[12];
    const float* gb0 = (const float*)d_in[13];
    const float* gw1 = (const float*)d_in[14];
    const float* gb1 = (const float*)d_in[15];
    float* out = (float*)d_out;

    unsigned* td_pk = (unsigned*)d_ws;                                 // 64 u32
    unsigned short* w0t = (unsigned short*)((char*)d_ws + 512);        // 2048 bf16
    unsigned short* w1t = (unsigned short*)((char*)d_ws + 512 + 4096); // 8192 bf16

    hipLaunchKernelGGL(prep_kernel, dim3(1), dim3(256), 0, stream,
                       ew0, eb0, ew1, eb1, fw0, fb0, fw1, fb1, gw0, gw1,
                       td_pk, w0t, w1t);

    const int nblocks = (S_DIM * N_DIM) / (WAVES * APW);   // 1024
    hipLaunchKernelGGL(descr_mfma, dim3(nblocks), dim3(256), 0, stream,
                       inputs, input_types, neigh_list, length,
                       gb0, gb1, td_pk, w0t, w1t, out);
}

// Round 9
// 212.808 us; speedup vs baseline: 1.0415x; 1.0415x over previous
//
#include <hip/hip_runtime.h>
#include <math.h>

#define S_DIM 8
#define N_DIM 2048
#define K_DIM 64
#define APW 2          // atoms per wave (R9: ONLY change vs R7 — TLP bisection)
#define WAVES 4        // waves per block (independent, no cross-wave sync in loop)
// h1 tile buffer geometry: 4x16 bf16 tiles (128 B) + 16 B pad, [q_t][jt] grid
#define TQ 144         // tile stride, bytes
#define TJ (4 * TQ)    // jt stride
#define SLICE 3392     // per-wave LDS slice: s_rt 1088 + h1t/s_A 2304

typedef __attribute__((ext_vector_type(8))) short bf16x8;
typedef __attribute__((ext_vector_type(4))) float f32x4;
typedef __attribute__((ext_vector_type(4))) int   i32x4;
typedef __attribute__((ext_vector_type(2))) int   i32x2;

__device__ __forceinline__ unsigned asu(float x) {
    union { float f; unsigned u; } v; v.f = x; return v.u;
}
__device__ __forceinline__ unsigned short f2bf(float x) {
    unsigned u = asu(x);
    return (unsigned short)((u + 0x7FFFu + ((u >> 16) & 1u)) >> 16);
}
__device__ __forceinline__ float lo16f(int d) {
    union { unsigned u; float f; } v; v.u = ((unsigned)d) << 16; return v.f;
}
__device__ __forceinline__ float hi16f(int d) {
    union { unsigned u; float f; } v; v.u = ((unsigned)d) & 0xFFFF0000u; return v.f;
}
// RNE packed pair — integer-ALU form, bit-identical to baseline.
// NOTE: v_cvt_pk_bf16_f32 is BANNED this session — two failed attempts (R2
// absmax 524, R8 NaN) show our model of its semantics on gfx950 is wrong.
__device__ __forceinline__ unsigned rne_pk(float x, float y) {
    unsigned ux = asu(x), uy = asu(y);
    return ((ux + 0x7FFFu + ((ux >> 16) & 1u)) >> 16) |
           ((uy + 0x7FFFu + ((uy >> 16) & 1u)) & 0xFFFF0000u);
}
// truncation packed pair (L2 g operand, as baseline)
__device__ __forceinline__ unsigned trn_pk(float x, float y) {
    return (asu(x) >> 16) | (asu(y) & 0xFFFF0000u);
}
// Wave-local LDS fence (slices are wave-private; weights are read-only after
// the one startup barrier). Proven correct R3/R4/R6/R7.
__device__ __forceinline__ void lds_fence() {
    asm volatile("s_waitcnt lgkmcnt(0)" ::: "memory");
    __builtin_amdgcn_sched_barrier(0);
}
// K<=16 MFMA from two packed bf16-pair dwords per operand (zero-padded K=32).
__device__ __forceinline__ f32x4 mfma_k16(unsigned a0, unsigned a1,
                                          unsigned b0, unsigned b1, f32x4 c) {
    union { i32x4 i; bf16x8 b; } ua, ub;
    ua.i = (i32x4){(int)a0, (int)a1, 0, 0};
    ub.i = (i32x4){(int)b0, (int)b1, 0, 0};
    return __builtin_amdgcn_mfma_f32_16x16x32_bf16(ua.b, ub.b, c, 0, 0, 0);
}

// ---------------------------------------------------------------------------
// Prep: packed td table + bf16 weights (unchanged).
// ---------------------------------------------------------------------------
__global__ __launch_bounds__(256) void prep_kernel(
        const float* __restrict__ ew0, const float* __restrict__ eb0,
        const float* __restrict__ ew1, const float* __restrict__ eb1,
        const float* __restrict__ fw0, const float* __restrict__ fb0,
        const float* __restrict__ fw1, const float* __restrict__ fb1,
        const float* __restrict__ gw0, const float* __restrict__ gw1,
        unsigned* __restrict__ td_pk,
        unsigned short* __restrict__ w0t, unsigned short* __restrict__ w1t) {
    __shared__ float l_ew0[32], l_eb0[16], l_ew1[512], l_eb1[32];
    __shared__ float l_fw0[1024], l_fb0[32], l_fw1[992], l_fb1[31];
    __shared__ float l_h[4][2][16];
    __shared__ float l_tv[4][32];
    __shared__ float l_f1[4][32];
    __shared__ float l_td[4][32];

    const int tid = threadIdx.x;
    if (tid < 32) l_ew0[tid] = ew0[tid];
    if (tid < 16) l_eb0[tid] = eb0[tid];
    for (int i = tid; i < 512; i += 256) l_ew1[i] = ew1[i];
    if (tid < 32) l_eb1[tid] = eb1[tid];
    for (int i = tid; i < 1024; i += 256) l_fw0[i] = fw0[i];
    if (tid < 32) l_fb0[tid] = fb0[tid];
    for (int i = tid; i < 992; i += 256) l_fw1[i] = fw1[i];
    if (tid < 31) l_fb1[tid] = fb1[tid];
    __syncthreads();

    if (tid < 128) {
        const int p = tid >> 5, ord = (tid >> 4) & 1, j = tid & 15;
        const float c = (float)(p >> 1), t = (float)(p & 1);
        const float x0 = ord ? t : c;
        const float x1 = ord ? c : t;
        l_h[p][ord][j] = fmaxf(x0 * l_ew0[j] + x1 * l_ew0[16 + j] + l_eb0[j], 0.f);
    }
    __syncthreads();
    if (tid < 128) {
        const int p = tid >> 5, j = tid & 31;
        float acc = 0.f;
#pragma unroll
        for (int ord = 0; ord < 2; ord++) {
            float v = l_eb1[j];
#pragma unroll
            for (int i = 0; i < 16; i++) v += l_h[p][ord][i] * l_ew1[i * 32 + j];
            acc += fmaxf(v, 0.f);
        }
        l_tv[p][j] = acc;
    }
    __syncthreads();
    if (tid < 128) {
        const int p = tid >> 5, j = tid & 31;
        float v = l_fb0[j];
#pragma unroll
        for (int i = 0; i < 32; i++) v += l_tv[p][i] * l_fw0[i * 32 + j];
        l_f1[p][j] = fmaxf(v, 0.f);
    }
    __syncthreads();
    if (tid < 128) {
        const int p = tid >> 5, j = tid & 31;
        if (j < 31) {
            float v = l_fb1[j];
#pragma unroll
            for (int i = 0; i < 32; i++) v += l_f1[p][i] * l_fw1[i * 31 + j];
            l_td[p][j] = fmaxf(v, 0.f);
        } else {
            l_td[p][31] = 0.f;
        }
    }
    __syncthreads();
    if (tid < 64) {   // td_pk[p*16+i] = bf(td[2i]) | bf(td[2i+1])<<16
        const int p = tid >> 4, i = tid & 15;
        const unsigned lo = f2bf(l_td[p][2 * i]);
        const unsigned hi = (i == 15) ? 0u : (unsigned)f2bf(l_td[p][2 * i + 1]);
        td_pk[tid] = lo | (hi << 16);
    }

    for (int idx = tid; idx < 2048; idx += 256) {   // W0T[j*32+i] = gw0[i][j]
        const int j = idx >> 5, i = idx & 31;
        w0t[idx] = f2bf(gw0[i * 64 + j]);
    }
    for (int idx = tid; idx < 8192; idx += 256) {   // W1T[e*64+j] = gw1[j][e]
        const int e = idx >> 6, j = idx & 63;
        w1t[idx] = f2bf(gw1[j * 128 + e]);
    }
}

// ---------------------------------------------------------------------------
// Main. R9 = R7 (passed, absmax 128) with ONE change: APW 4->2 (grid 2048).
// Rationale: R6 counters showed OccupancyPercent ~19 (=6 waves/CU) with
// VALUBusy 40% — latency-bound with too few schedulable waves. APW=2 doubles
// total wave count to 8/SIMD of work for pure TLP, zero numerics change.
// (R8 bundled this with cvt_pk g-pack + b1-LDS and NaN'd; cvt_pk is banned —
// two failures R2/R8 — and b1-LDS is deferred until APW is bisected.)
// launch_bounds(256,3): cap ~170 — guaranteed no spill (R3 lesson).
// ---------------------------------------------------------------------------
__global__ __launch_bounds__(256, 3) void descr_mfma(
    const float* __restrict__ inputs, const int* __restrict__ input_types,
    const int* __restrict__ neigh_list, const float* __restrict__ length,
    const float* __restrict__ gb0, const float* __restrict__ gb1,
    const unsigned* __restrict__ td_pk, const unsigned short* __restrict__ w0t,
    const unsigned short* __restrict__ w1t, float* __restrict__ out)
{
    __shared__ __align__(16) char s_pool[WAVES * SLICE];   // 13568 B
    __shared__ __align__(16) char s_w1[16384];             // swizzled W1T
    __shared__ unsigned s_tdpk[64];                        // td table
    __shared__ float s_gb0f[64];                           // bias b0

    const int tid = threadIdx.x;
    const int lane = tid & 63;
    const int w = tid >> 6;
    const int l15 = lane & 15;
    const int q = lane >> 4;

    // ---- block-cooperative staging (once) -------------------------------
    if (tid < 64) { s_tdpk[tid] = td_pk[tid]; s_gb0f[tid] = gb0[tid]; }
    for (int m = tid; m < 1024; m += 256) {   // 1024 x 16B chunks of W1T
        const int e = m >> 3, c = m & 7;
        const i32x4 v = *(const i32x4*)&w1t[e * 64 + c * 8];
        *(i32x4*)(s_w1 + e * 128 + (((c + e) & 7) << 4)) = v;  // rotate chunks
    }
    __syncthreads();   // ONLY block barrier; loop below is wave-independent

    // ---- per-wave slice pointers ----------------------------------------
    char* const slice = s_pool + w * SLICE;
    float* const s_rt = (float*)slice;              // 1088 B
    char*  const h1t  = slice + 1088;               // 2304 B tiles
    float* const s_A  = (float*)(slice + 1088);     // overlay (h1 dead in D)
    const unsigned h1u = (unsigned)(unsigned long long)(const void*)h1t;

    const int wroff = (l15 >> 2) * TQ + (l15 & 3) * 32 + q * 8;          // tile write
    const unsigned troff = h1u + (unsigned)(q * TQ + (l15 >> 2) * 32 + (l15 & 3) * 8);
    const int aoff  = (l15 >> 2) * TQ + (l15 & 3) * 32 + (q & 1) * 16;   // L2 read
    const char* const w1r = s_w1 + l15 * 128;
    const int wo0 = ((q + l15) & 7) << 4;            // chunk rot, j = q*8..
    const int wo1 = ((q + 4 + l15) & 7) << 4;        // chunk rot, j = 32+q*8..

    // static small fragments (registers)
    bf16x8 w0f[4];
#pragma unroll
    for (int nt = 0; nt < 4; nt++)
        w0f[nt] = *(const bf16x8*)&w0t[(nt * 16 + l15) * 32 + q * 8];
    float b1f[8];
#pragma unroll
    for (int et = 0; et < 8; et++) b1f[et] = gb1[et * 16 + l15];

    const float Lx = length[0], Ly = length[1], Lz = length[2];
    const float iLx = 1.f / Lx, iLy = 1.f / Ly, iLz = 1.f / Lz;
    const f32x4 zf = {0.f, 0.f, 0.f, 0.f};

    const int abase = (blockIdx.x * WAVES + w) * APW;
    const int sidx = abase >> 11;   // APW atoms of a wave share s (abase even)

    // geometry pipeline state (current atom, prefetched one iter ahead)
    int   cnb  = neigh_list[abase * K_DIM + lane];
    float ccx  = inputs[abase * 3 + 0];
    float ccy  = inputs[abase * 3 + 1];
    float ccz  = inputs[abase * 3 + 2];
    int   cct  = input_types[abase];
    int   cidx0 = cnb < 0 ? 0 : cnb;
    float cpx  = inputs[(sidx * N_DIM + cidx0) * 3 + 0];
    float cpy  = inputs[(sidx * N_DIM + cidx0) * 3 + 1];
    float cpz  = inputs[(sidx * N_DIM + cidx0) * 3 + 2];
    int   cntp = input_types[sidx * N_DIM + cidx0];

    for (int aa = 0; aa < APW; aa++) {
        const int atom = abase + aa;
        const bool pf = (aa + 1 < APW);

        // stage-A prefetch for next atom
        int nnb = 0, nct = 0; float ncx = 0.f, ncy = 0.f, ncz = 0.f;
        if (pf) {
            nnb = neigh_list[(atom + 1) * K_DIM + lane];
            ncx = inputs[(atom + 1) * 3 + 0];
            ncy = inputs[(atom + 1) * 3 + 1];
            ncz = inputs[(atom + 1) * 3 + 2];
            nct = input_types[atom + 1];
        }

        lds_fence();   // s_rt overwrite vs prior rtp reads; s_A reads done

        // ---- geometry -> s_rt + packed per-lane info (NO st staging)
        unsigned pinfo;
        {
            const bool msk = cnb < 0;
            float dx = cpx - ccx;
            float dy = cpy - ccy;
            float dz = cpz - ccz;
            dx -= Lx * rintf(dx * iLx);
            dy -= Ly * rintf(dy * iLy);
            dz -= Lz * rintf(dz * iLz);
            const float rsq = dx * dx + dy * dy + dz * dz;
            const float r = sqrtf(rsq > 0.f ? rsq : 1.f);
            const float inv = 1.f / r;
            float sw;
            if (r < 6.f) sw = inv;
            else if (r < 12.f) {
                const float u = (r - 6.f) * (1.f / 6.f);
                sw = inv * (0.5f * __cosf(3.14159265358979323846f * u) + 0.5f);
            } else sw = 0.f;
            const bool valid = (!msk) && (rsq > 0.f);
            const float sij = valid ? sw : 0.f;
            const float f = sij * inv;
            s_rt[0 * 68 + lane] = sij;
            s_rt[1 * 68 + lane] = dx * f;
            s_rt[2 * 68 + lane] = dy * f;
            s_rt[3 * 68 + lane] = dz * f;
            pinfo = ((unsigned)f2bf(sij) << 16) |
                    (unsigned)((cct << 1) + cntp) | (msk ? 256u : 0u);
        }
        lds_fence();

        // ---- rt^T fragments, packed RNE pairs
        unsigned rtp[4][2];
#pragma unroll
        for (int a = 0; a < 4; a++) {
            const f32x4 rv = *(const f32x4*)&s_rt[(l15 & 3) * 68 + a * 16 + q * 4];
            rtp[a][0] = rne_pk(rv[0], rv[1]);
            rtp[a][1] = rne_pk(rv[2], rv[3]);
        }

        int nidx = 0, nntp = 0; float npx = 0.f, npy = 0.f, npz = 0.f;
        f32x4 Bj[4] = {zf, zf, zf, zf};
        f32x4 AT[8] = {zf, zf, zf, zf, zf, zf, zf, zf};

        // ---- per-16-k chunk: rebuild st from table -> L1^T -> tiles -> Bj/L2
#pragma unroll
        for (int mt = 0; mt < 4; mt++) {
            // neighbor-k info for k = mt*16+l15 (same source lane for all q)
            const unsigned pk =
                (unsigned)__builtin_amdgcn_ds_bpermute((mt * 16 + l15) << 2, (int)pinfo);
            const unsigned pair = pk & 3u;
            const unsigned zm = (pk & 256u) ? 0u : 0xFFFFFFFFu;
            const unsigned ksij = pk & 0xFFFF0000u;
            const unsigned* trow = &s_tdpk[pair * 16];
            // st[k][i=q*8..+7] (B-operand) and residual dword-pairs
            i32x4 tq = *(const i32x4*)&trow[q * 4];
            i32x2 rd0 = *(const i32x2*)&trow[2 * q];
            i32x2 rd1 = *(const i32x2*)&trow[8 + 2 * q];
            tq[0] = (int)((unsigned)tq[0] & zm);
            tq[1] = (int)((unsigned)tq[1] & zm);
            tq[2] = (int)((unsigned)tq[2] & zm);
            tq[3] = (int)((unsigned)tq[3] & zm);
            rd0[0] = (int)((unsigned)rd0[0] & zm);
            rd0[1] = (int)((unsigned)rd0[1] & zm);
            rd1[0] = (int)((unsigned)rd1[0] & zm);
            rd1[1] = (int)((unsigned)rd1[1] & zm);
            if (q == 3) {   // i=31 <- sij (tq dword3 hi16; rd1 dword1 hi16)
                tq[3]  = (int)(((unsigned)tq[3]  & 0xFFFFu) | ksij);
                rd1[1] = (int)(((unsigned)rd1[1] & 0xFFFFu) | ksij);
            }
            union { i32x4 i; bf16x8 b; } ua; ua.i = tq;
            const bf16x8 afr = ua.b;

            f32x4 c1[4];
#pragma unroll
            for (int jt = 0; jt < 4; jt++)   // TRANSPOSED L1: A=W0^T, B=st
                c1[jt] = __builtin_amdgcn_mfma_f32_16x16x32_bf16(w0f[jt], afr, zf, 0, 0, 0);

            // epilogue: lane holds h1[k=mt*16+l15][j=jt*16+q*4+reg]
#pragma unroll
            for (int jt = 0; jt < 4; jt++) {
                const f32x4 bb = *(const f32x4*)&s_gb0f[jt * 16 + q * 4];
                const i32x2 rr = (jt & 1) ? rd1 : rd0;
                const float h0 = fmaxf(c1[jt][0] + bb[0], 0.f) + lo16f(rr[0]);
                const float h1 = fmaxf(c1[jt][1] + bb[1], 0.f) + hi16f(rr[0]);
                const float h2 = fmaxf(c1[jt][2] + bb[2], 0.f) + lo16f(rr[1]);
                const float h3 = fmaxf(c1[jt][3] + bb[3], 0.f) + hi16f(rr[1]);
                i32x2 pkv;
                pkv[0] = (int)rne_pk(h0, h1);
                pkv[1] = (int)rne_pk(h2, h3);
                *(i32x2*)(h1t + wroff + jt * TJ) = pkv;
            }
            if (mt == 0 && pf) {   // stage-B prefetch (ample slack)
                nidx = nnb < 0 ? 0 : nnb;
                const int nbase = (sidx * N_DIM + nidx) * 3;
                npx = inputs[nbase + 0];
                npy = inputs[nbase + 1];
                npz = inputs[nbase + 2];
                nntp = input_types[sidx * N_DIM + nidx];
            }
            lds_fence();   // tile writes -> reads handoff (same-wave DS in order)

            // Bj B-operand: cooperative tr-read (R6-verified addressing)
            i32x2 t0, t1, t2, t3;
            asm volatile("ds_read_b64_tr_b16 %0, %1" : "=v"(t0) : "v"(troff));
            asm volatile("ds_read_b64_tr_b16 %0, %1" : "=v"(t1) : "v"(troff + TJ));
            asm volatile("ds_read_b64_tr_b16 %0, %1" : "=v"(t2) : "v"(troff + 2 * TJ));
            asm volatile("ds_read_b64_tr_b16 %0, %1" : "=v"(t3) : "v"(troff + 3 * TJ));
            asm volatile("s_waitcnt lgkmcnt(0)" ::: "memory");
            __builtin_amdgcn_sched_barrier(0);
            Bj[0] = mfma_k16(rtp[mt][0], rtp[mt][1], (unsigned)t0[0], (unsigned)t0[1], Bj[0]);
            Bj[1] = mfma_k16(rtp[mt][0], rtp[mt][1], (unsigned)t1[0], (unsigned)t1[1], Bj[1]);
            Bj[2] = mfma_k16(rtp[mt][0], rtp[mt][1], (unsigned)t2[0], (unsigned)t2[1], Bj[2]);
            Bj[3] = mfma_k16(rtp[mt][0], rtp[mt][1], (unsigned)t3[0], (unsigned)t3[1], Bj[3]);

            // L2: A-frag h1[k=mt*16+l15][j] from tiles; W1 from swizzled LDS
            const bf16x8 a0 = *(const bf16x8*)(h1t + aoff + (q >> 1) * TJ);
            const bf16x8 a1 = *(const bf16x8*)(h1t + aoff + (2 + (q >> 1)) * TJ);
#pragma unroll
            for (int et = 0; et < 8; et++) {
                const bf16x8 wf0 = *(const bf16x8*)(w1r + et * 2048 + wo0);
                const bf16x8 wf1 = *(const bf16x8*)(w1r + et * 2048 + wo1);
                f32x4 c2 = __builtin_amdgcn_mfma_f32_16x16x32_bf16(a0, wf0, zf, 0, 0, 0);
                c2 = __builtin_amdgcn_mfma_f32_16x16x32_bf16(a1, wf1, c2, 0, 0, 0);
                const float g0 = fmaxf(c2[0] + b1f[et], 0.f);
                const float g1 = fmaxf(c2[1] + b1f[et], 0.f);
                const float g2 = fmaxf(c2[2] + b1f[et], 0.f);
                const float g3 = fmaxf(c2[3] + b1f[et], 0.f);
                AT[et] = mfma_k16(rtp[mt][0], rtp[mt][1],
                                  trn_pk(g0, g1), trn_pk(g2, g3), AT[et]);
            }
        }

        // ---- A = AT + Bj[e&3]; rows d=0..3 live in q==0 lanes
        if (lane < 16) {
#pragma unroll
            for (int et = 0; et < 8; et++) {
                const f32x4 v = AT[et] + Bj[et & 3];
                *(f32x4*)&s_A[(et * 16 + lane) * 4] = v;
            }
        }
        lds_fence();

        // ---- D[e][m] = dot(A[e], A[m]); coalesced float4 stores
        {
            const int m0 = (lane & 3) * 4;
            const int er = lane >> 2;
            f32x4 Am[4];
#pragma unroll
            for (int t = 0; t < 4; t++) Am[t] = *(const f32x4*)&s_A[(m0 + t) * 4];
            float* op = out + (size_t)atom * 2048;
#pragma unroll
            for (int g = 0; g < 8; g++) {
                const int e = g * 16 + er;
                const f32x4 Ae = *(const f32x4*)&s_A[e * 4];
                f32x4 o;
                o[0] = Ae[0]*Am[0][0] + Ae[1]*Am[0][1] + Ae[2]*Am[0][2] + Ae[3]*Am[0][3];
                o[1] = Ae[0]*Am[1][0] + Ae[1]*Am[1][1] + Ae[2]*Am[1][2] + Ae[3]*Am[1][3];
                o[2] = Ae[0]*Am[2][0] + Ae[1]*Am[2][1] + Ae[2]*Am[2][2] + Ae[3]*Am[2][3];
                o[3] = Ae[0]*Am[3][0] + Ae[1]*Am[3][1] + Ae[2]*Am[3][2] + Ae[3]*Am[3][3];
                *(f32x4*)&op[e * 16 + m0] = o;
            }
        }

        // rotate prefetched geometry state
        cnb = nnb; ccx = ncx; ccy = ncy; ccz = ncz; cct = nct;
        cpx = npx; cpy = npy; cpz = npz; cntp = nntp;
    }
}

extern "C" void kernel_launch(void* const* d_in, const int* in_sizes, int n_in,
                              void* d_out, int out_size, void* d_ws, size_t ws_size,
                              hipStream_t stream) {
    (void)in_sizes; (void)n_in; (void)out_size; (void)ws_size;
    const float* inputs      = (const float*)d_in[0];
    const int*   input_types = (const int*)d_in[1];
    const int*   neigh_list  = (const int*)d_in[2];
    const float* length      = (const float*)d_in[3];
    const float* ew0 = (const float*)d_in[4];
    const float* eb0 = (const float*)d_in[5];
    const float* ew1 = (const float*)d_in[6];
    const float* eb1 = (const float*)d_in[7];
    const float* fw0 = (const float*)d_in[8];
    const float* fb0 = (const float*)d_in[9];
    const float* fw1 = (const float*)d_in[10];
    const float* fb1 = (const float*)d_in[11];
    const float* gw0 = (const float*)d_in[12];
    const float* gb0 = (const float*)d_in[13];
    const float* gw1 = (const float*)d_in[14];
    const float* gb1 = (const float*)d_in[15];
    float* out = (float*)d_out;

    unsigned* td_pk = (unsigned*)d_ws;                                 // 64 u32
    unsigned short* w0t = (unsigned short*)((char*)d_ws + 512);        // 2048 bf16
    unsigned short* w1t = (unsigned short*)((char*)d_ws + 512 + 4096); // 8192 bf16

    hipLaunchKernelGGL(prep_kernel, dim3(1), dim3(256), 0, stream,
                       ew0, eb0, ew1, eb1, fw0, fb0, fw1, fb1, gw0, gw1,
                       td_pk, w0t, w1t);

    const int nblocks = (S_DIM * N_DIM) / (WAVES * APW);   // 2048
    hipLaunchKernelGGL(descr_mfma, dim3(nblocks), dim3(256), 0, stream,
                       inputs, input_types, neigh_list, length,
                       gb0, gb1, td_pk, w0t, w1t, out);
}